// Round 1
// baseline (8200.905 us; speedup 1.0000x reference)
//
#include <hip/hip_runtime.h>
#include <math.h>

#define B 16
#define S 512
#define IN 64
#define D 512
#define H 8
#define DK 64
#define L 6
#define F 2048
#define BS (B*S)          /* 8192 */
#define EPS 1e-5f

// ---------------------------------------------------------------------------
// Relative positional encoding, reduced analytically:
// pe[k][d] = (1/S) * sum_q rel_emb[clip(q-k,-32,32)+32][d]
//          = (1/S) * [ max(0,k-31)*emb[0] + max(0,S-k-32)*emb[64]
//                      + sum_{r=1..63} [0 <= k+r-32 < S] * emb[r] ]
// ---------------------------------------------------------------------------
__global__ __launch_bounds__(256) void pe_kernel(const float* __restrict__ rel_emb,
                                                 float* __restrict__ pe) {
    int k = blockIdx.x;       // 0..S-1
    int d = threadIdx.x;      // 0..255 ; handles d and d+256
    float acc0 = 0.f, acc1 = 0.f;
    for (int r = 0; r < 65; ++r) {
        float w;
        if (r == 0)       w = (float)max(0, k - 31);
        else if (r == 64) w = (float)max(0, S - (k + 32));
        else {
            int qpos = k + r - 32;
            w = (qpos >= 0 && qpos < S) ? 1.f : 0.f;
        }
        acc0 += w * rel_emb[r * D + d];
        acc1 += w * rel_emb[r * D + d + 256];
    }
    pe[k * D + d]       = acc0 * (1.f / (float)S);
    pe[k * D + d + 256] = acc1 * (1.f / (float)S);
}

// ---------------------------------------------------------------------------
// fp32 SIMT GEMM: C = A(MxK) @ W(KxN) + bias, tile 128x128x16, 256 thr, 8x8/thr
// mode 0: bias          mode 1: bias+relu
// mode 2: bias + pe[row%S][col]      (input projection)
// mode 3: bias + scatter to (B,H,S,DK) layout (q/k/v proj, grid.z picks slice)
// ---------------------------------------------------------------------------
#define BMT 128
#define BNT 128
#define BKT 16

__global__ __launch_bounds__(256) void sgemm_kernel(
    const float* __restrict__ A, const float* __restrict__ W,
    const float* __restrict__ bias, float* __restrict__ C,
    int M, int N, int K, int mode, const float* __restrict__ pe,
    int wstride, int bstride, long cstride)
{
    __shared__ float As[BKT][BMT + 4];
    __shared__ float Bs[BKT][BNT];

    const int z = blockIdx.z;
    const float* Wz = W    + (size_t)z * wstride;
    const float* bz = bias + (size_t)z * bstride;
    float*       Cz = C    + (size_t)z * cstride;

    const int bm = blockIdx.y, bn = blockIdx.x;
    const int t  = threadIdx.x;
    const int tx = t & 15, ty = t >> 4;

    float acc[8][8];
#pragma unroll
    for (int i = 0; i < 8; ++i)
#pragma unroll
        for (int j = 0; j < 8; ++j) acc[i][j] = 0.f;

    const int arow  = t >> 2;         // 0..63
    const int acol4 = (t & 3) * 4;    // 0,4,8,12
    const int brow  = t >> 5;         // 0..7
    const int bcol4 = (t & 31) * 4;   // 0..124

    const float* Aptr = A + (size_t)(bm * BMT) * K;

    for (int kt = 0; kt < K; kt += BKT) {
        float4 a0 = *(const float4*)(Aptr + (size_t)arow        * K + kt + acol4);
        float4 a1 = *(const float4*)(Aptr + (size_t)(arow + 64) * K + kt + acol4);
        float4 b0 = *(const float4*)(Wz + (size_t)(kt + brow)     * N + bn * BNT + bcol4);
        float4 b1 = *(const float4*)(Wz + (size_t)(kt + brow + 8) * N + bn * BNT + bcol4);
        __syncthreads();
        As[acol4 + 0][arow] = a0.x;
        As[acol4 + 1][arow] = a0.y;
        As[acol4 + 2][arow] = a0.z;
        As[acol4 + 3][arow] = a0.w;
        As[acol4 + 0][arow + 64] = a1.x;
        As[acol4 + 1][arow + 64] = a1.y;
        As[acol4 + 2][arow + 64] = a1.z;
        As[acol4 + 3][arow + 64] = a1.w;
        *(float4*)&Bs[brow][bcol4]     = b0;
        *(float4*)&Bs[brow + 8][bcol4] = b1;
        __syncthreads();
#pragma unroll
        for (int kk = 0; kk < BKT; ++kk) {
            float a[8], b[8];
            *(float4*)&a[0] = *(const float4*)&As[kk][ty * 4];
            *(float4*)&a[4] = *(const float4*)&As[kk][64 + ty * 4];
            *(float4*)&b[0] = *(const float4*)&Bs[kk][tx * 4];
            *(float4*)&b[4] = *(const float4*)&Bs[kk][64 + tx * 4];
#pragma unroll
            for (int i = 0; i < 8; ++i)
#pragma unroll
                for (int j = 0; j < 8; ++j)
                    acc[i][j] += a[i] * b[j];
        }
    }

    // epilogue
#pragma unroll
    for (int ri = 0; ri < 8; ++ri) {
        int row = bm * BMT + ((ri < 4) ? (ty * 4 + ri) : (64 + ty * 4 + ri - 4));
#pragma unroll
        for (int cg = 0; cg < 2; ++cg) {
            int col = bn * BNT + cg * 64 + tx * 4;
            float4 v;
            v.x = acc[ri][cg * 4 + 0];
            v.y = acc[ri][cg * 4 + 1];
            v.z = acc[ri][cg * 4 + 2];
            v.w = acc[ri][cg * 4 + 3];
            float4 bb = *(const float4*)(bz + col);
            v.x += bb.x; v.y += bb.y; v.z += bb.z; v.w += bb.w;
            if (mode == 1) {
                v.x = fmaxf(v.x, 0.f); v.y = fmaxf(v.y, 0.f);
                v.z = fmaxf(v.z, 0.f); v.w = fmaxf(v.w, 0.f);
            } else if (mode == 2) {
                float4 pp = *(const float4*)(pe + (size_t)(row & (S - 1)) * D + col);
                v.x += pp.x; v.y += pp.y; v.z += pp.z; v.w += pp.w;
            }
            if (mode == 3) {
                int bi = row >> 9, si = row & (S - 1);
                int hh = col >> 6, dd = col & 63;
                *(float4*)(Cz + (((size_t)(bi * H + hh) * S + si) * DK + dd)) = v;
            } else {
                *(float4*)(Cz + (size_t)row * N + col) = v;
            }
        }
    }
}

// ---------------------------------------------------------------------------
// Flash-style attention: one thread per q-row (q, ctx in registers),
// K/V staged in 64-row LDS tiles (same-address broadcast reads -> no conflicts)
// q,k,v layouts: (B*H, S, DK). Output ctx written in (B, S, D) layout.
// ---------------------------------------------------------------------------
__global__ __launch_bounds__(256) void attn_kernel(
    const float* __restrict__ qb, const float* __restrict__ kb,
    const float* __restrict__ vb, float* __restrict__ ctx)
{
    __shared__ float kT[64][64];
    __shared__ float vT[64][64];
    const int t  = threadIdx.x;
    const int qc = blockIdx.x & 1;        // which half of S
    const int bh = blockIdx.x >> 1;       // 0..B*H-1
    const int bi = bh >> 3, hh = bh & 7;
    const int srow = qc * 256 + t;

    float q[64];
    const float* qrow = qb + ((size_t)bh * S + srow) * DK;
#pragma unroll
    for (int d4 = 0; d4 < 64; d4 += 4)
        *(float4*)&q[d4] = *(const float4*)(qrow + d4);

    float ctxr[64];
#pragma unroll
    for (int d = 0; d < 64; ++d) ctxr[d] = 0.f;
    float m = -INFINITY, l = 0.f;

    const float* kbase = kb + (size_t)bh * S * DK;
    const float* vbase = vb + (size_t)bh * S * DK;

    for (int jt = 0; jt < S; jt += 64) {
        __syncthreads();
#pragma unroll
        for (int u = 0; u < 4; ++u) {
            int idx = t + u * 256;        // float4 index 0..1023
            int r = idx >> 4;
            int c = (idx & 15) * 4;
            *(float4*)&kT[r][c] = *(const float4*)(kbase + (size_t)(jt + r) * DK + c);
            *(float4*)&vT[r][c] = *(const float4*)(vbase + (size_t)(jt + r) * DK + c);
        }
        __syncthreads();
#pragma unroll
        for (int sub = 0; sub < 4; ++sub) {
            float sc[16];
#pragma unroll
            for (int jj = 0; jj < 16; ++jj) {
                int j = sub * 16 + jj;
                float s0 = 0.f;
#pragma unroll
                for (int d4 = 0; d4 < 64; d4 += 4) {
                    float4 kk = *(const float4*)&kT[j][d4];
                    s0 += q[d4 + 0] * kk.x + q[d4 + 1] * kk.y
                        + q[d4 + 2] * kk.z + q[d4 + 3] * kk.w;
                }
                sc[jj] = s0 * 0.125f;     // 1/sqrt(64)
            }
            float mt = sc[0];
#pragma unroll
            for (int jj = 1; jj < 16; ++jj) mt = fmaxf(mt, sc[jj]);
            float m_new = fmaxf(m, mt);
            float alpha = __expf(m - m_new);
            l *= alpha;
#pragma unroll
            for (int d = 0; d < 64; ++d) ctxr[d] *= alpha;
#pragma unroll
            for (int jj = 0; jj < 16; ++jj) {
                int j = sub * 16 + jj;
                float p = __expf(sc[jj] - m_new);
                l += p;
#pragma unroll
                for (int d4 = 0; d4 < 64; d4 += 4) {
                    float4 vv = *(const float4*)&vT[j][d4];
                    ctxr[d4 + 0] += p * vv.x;
                    ctxr[d4 + 1] += p * vv.y;
                    ctxr[d4 + 2] += p * vv.z;
                    ctxr[d4 + 3] += p * vv.w;
                }
            }
            m = m_new;
        }
    }
    float inv = 1.f / l;
    float* cp = ctx + ((size_t)bi * S + srow) * D + hh * DK;
#pragma unroll
    for (int d4 = 0; d4 < 64; d4 += 4) {
        float4 o;
        o.x = ctxr[d4 + 0] * inv;
        o.y = ctxr[d4 + 1] * inv;
        o.z = ctxr[d4 + 2] * inv;
        o.w = ctxr[d4 + 3] * inv;
        *(float4*)(cp + d4) = o;
    }
}

// ---------------------------------------------------------------------------
// Fused residual + LayerNorm: out = LN(a + b) * g + beta ; one block per row
// ---------------------------------------------------------------------------
__global__ __launch_bounds__(128) void ln_kernel(
    const float* __restrict__ a, const float* __restrict__ bres,
    const float* __restrict__ g, const float* __restrict__ beta,
    float* __restrict__ out)
{
    const int row = blockIdx.x;
    const int t = threadIdx.x;           // 0..127, 4 elems each
    const float4 xa = *(const float4*)(a    + (size_t)row * D + t * 4);
    const float4 xb = *(const float4*)(bres + (size_t)row * D + t * 4);
    float x0 = xa.x + xb.x, x1 = xa.y + xb.y, x2 = xa.z + xb.z, x3 = xa.w + xb.w;
    float s  = x0 + x1 + x2 + x3;
    float s2 = x0 * x0 + x1 * x1 + x2 * x2 + x3 * x3;
#pragma unroll
    for (int o = 32; o > 0; o >>= 1) {
        s  += __shfl_down(s, o);
        s2 += __shfl_down(s2, o);
    }
    __shared__ float red[2][2];
    const int wave = t >> 6;
    if ((t & 63) == 0) { red[wave][0] = s; red[wave][1] = s2; }
    __syncthreads();
    s  = red[0][0] + red[1][0];
    s2 = red[0][1] + red[1][1];
    const float mu  = s * (1.f / (float)D);
    const float var = s2 * (1.f / (float)D) - mu * mu;
    const float r   = rsqrtf(var + EPS);
    const float4 gg = *(const float4*)(g    + t * 4);
    const float4 bb = *(const float4*)(beta + t * 4);
    float4 o;
    o.x = (x0 - mu) * r * gg.x + bb.x;
    o.y = (x1 - mu) * r * gg.y + bb.y;
    o.z = (x2 - mu) * r * gg.z + bb.z;
    o.w = (x3 - mu) * r * gg.w + bb.w;
    *(float4*)(out + (size_t)row * D + t * 4) = o;
}

// ---------------------------------------------------------------------------
// Output projection: out[row] = h[row,:] . out_W + out_b ; one wave per row
// ---------------------------------------------------------------------------
__global__ __launch_bounds__(256) void out_kernel(
    const float* __restrict__ h, const float* __restrict__ ow,
    const float* __restrict__ ob, float* __restrict__ out)
{
    const int wave = threadIdx.x >> 6;
    const int lane = threadIdx.x & 63;
    const int row  = blockIdx.x * 4 + wave;
    const float* hp = h + (size_t)row * D;
    float s = 0.f;
#pragma unroll
    for (int u = 0; u < 8; ++u) {
        int d = lane + u * 64;
        s += hp[d] * ow[d];
    }
#pragma unroll
    for (int o = 32; o > 0; o >>= 1) s += __shfl_down(s, o);
    if (lane == 0) out[row] = s + ob[0];
}

// ---------------------------------------------------------------------------
extern "C" void kernel_launch(void* const* d_in, const int* in_sizes, int n_in,
                              void* d_out, int out_size, void* d_ws, size_t ws_size,
                              hipStream_t stream) {
    const float* x       = (const float*)d_in[0];
    const float* in_W    = (const float*)d_in[1];
    const float* in_b    = (const float*)d_in[2];
    const float* rel_emb = (const float*)d_in[3];
    const float* qkvo_W  = (const float*)d_in[4];
    const float* qkvo_b  = (const float*)d_in[5];
    const float* ln_g    = (const float*)d_in[6];
    const float* ln_bb   = (const float*)d_in[7];
    const float* ff_W1   = (const float*)d_in[8];
    const float* ff_b1   = (const float*)d_in[9];
    const float* ff_W2   = (const float*)d_in[10];
    const float* ff_b2   = (const float*)d_in[11];
    const float* out_W   = (const float*)d_in[12];
    const float* out_b   = (const float*)d_in[13];
    float* out = (float*)d_out;

    float* ws  = (float*)d_ws;
    const size_t HSZ = (size_t)BS * D;            // 4.19M floats
    float* h   = ws;
    float* tmp = h   + HSZ;
    float* h1  = tmp + HSZ;                        // also ctx buffer
    float* U   = h1  + HSZ;                        // qkv (12.6M) / ff (16.8M)
    float* pe  = U   + (size_t)BS * F;
    float* qb  = U;
    float* kb  = U + (size_t)B * H * S * DK;
    float* vb  = kb + (size_t)B * H * S * DK;

    dim3 blk(256);

    pe_kernel<<<dim3(S), blk, 0, stream>>>(rel_emb, pe);

    // input projection + pe: h = x @ in_W + in_b + pe[s]
    sgemm_kernel<<<dim3(D / BNT, BS / BMT, 1), blk, 0, stream>>>(
        x, in_W, in_b, h, BS, D, IN, 2, pe, 0, 0, 0);

    for (int l = 0; l < L; ++l) {
        const float* Wl = qkvo_W + (size_t)l * 4 * D * D;
        const float* bl = qkvo_b + (size_t)l * 4 * D;
        // q,k,v projections (grid.z = 3), scatter to (B,H,S,DK)
        sgemm_kernel<<<dim3(D / BNT, BS / BMT, 3), blk, 0, stream>>>(
            h, Wl, bl, U, BS, D, D, 3, nullptr, D * D, D, (long)B * H * S * DK);
        // attention -> ctx in (B,S,D) layout (stored in h1 buffer)
        attn_kernel<<<dim3(B * H * 2), blk, 0, stream>>>(qb, kb, vb, h1);
        // output projection: tmp = ctx @ W[3] + b[3]
        sgemm_kernel<<<dim3(D / BNT, BS / BMT, 1), blk, 0, stream>>>(
            h1, Wl + (size_t)3 * D * D, bl + 3 * D, tmp, BS, D, D, 0, nullptr, 0, 0, 0);
        // h1 = LN(h + tmp)
        ln_kernel<<<dim3(BS), dim3(128), 0, stream>>>(
            h, tmp, ln_g + (size_t)l * 2 * D, ln_bb + (size_t)l * 2 * D, h1);
        // ff1 = relu(h1 @ W1 + b1)
        sgemm_kernel<<<dim3(F / BNT, BS / BMT, 1), blk, 0, stream>>>(
            h1, ff_W1 + (size_t)l * D * F, ff_b1 + (size_t)l * F, U, BS, F, D, 1, nullptr, 0, 0, 0);
        // tmp = ff1 @ W2 + b2
        sgemm_kernel<<<dim3(D / BNT, BS / BMT, 1), blk, 0, stream>>>(
            U, ff_W2 + (size_t)l * F * D, ff_b2 + (size_t)l * D, tmp, BS, D, F, 0, nullptr, 0, 0, 0);
        // h = LN(h1 + tmp)
        ln_kernel<<<dim3(BS), dim3(128), 0, stream>>>(
            h1, tmp, ln_g + (size_t)l * 2 * D + D, ln_bb + (size_t)l * 2 * D + D, h);
    }

    out_kernel<<<dim3(BS / 4), blk, 0, stream>>>(h, out_W, out_b, out);
}

// Round 3
// 1448.782 us; speedup vs baseline: 5.6606x; 5.6606x over previous
//
#include <hip/hip_runtime.h>
#include <math.h>

#define B 16
#define S 512
#define IN 64
#define D 512
#define H 8
#define DK 64
#define L 6
#define F 2048
#define BS (B*S)          /* 8192 */
#define EPS 1e-5f

typedef short short8 __attribute__((ext_vector_type(8)));
typedef short short4v __attribute__((ext_vector_type(4)));
typedef float floatx4 __attribute__((ext_vector_type(4)));

static __device__ inline short f2bf(float x) {
    unsigned u = __float_as_uint(x);
    unsigned r = (u + 0x7fffu + ((u >> 16) & 1u)) >> 16;
    return (short)r;
}

// ---------------------------------------------------------------------------
// pe[k][d] = (1/S) * sum_q rel_emb[clip(q-k,-32,32)+32][d]   (closed form)
// ---------------------------------------------------------------------------
__global__ __launch_bounds__(256) void pe_kernel(const float* __restrict__ rel_emb,
                                                 float* __restrict__ pe) {
    int k = blockIdx.x;
    int d = threadIdx.x;
    float acc0 = 0.f, acc1 = 0.f;
    for (int r = 0; r < 65; ++r) {
        float w;
        if (r == 0)       w = (float)max(0, k - 31);
        else if (r == 64) w = (float)max(0, S - (k + 32));
        else {
            int qpos = k + r - 32;
            w = (qpos >= 0 && qpos < S) ? 1.f : 0.f;
        }
        acc0 += w * rel_emb[r * D + d];
        acc1 += w * rel_emb[r * D + d + 256];
    }
    pe[k * D + d]       = acc0 * (1.f / (float)S);
    pe[k * D + d + 256] = acc1 * (1.f / (float)S);
}

// ---------------------------------------------------------------------------
// Weight transpose + bf16 convert: src (z,K,N) f32 -> dst (z,N,K) bf16
// ---------------------------------------------------------------------------
__global__ __launch_bounds__(256) void wtrans_kernel(const float* __restrict__ src,
                                                     short* __restrict__ dst,
                                                     int K, int N) {
    __shared__ float Ls[32][33];
    const int z = blockIdx.z, kb = blockIdx.y, nb = blockIdx.x;
    const int tx = threadIdx.x & 31, ty = threadIdx.x >> 5;
    src += (size_t)z * K * N;
    dst += (size_t)z * K * N;
#pragma unroll
    for (int i = 0; i < 4; ++i)
        Ls[ty + i * 8][tx] = src[(size_t)(kb * 32 + ty + i * 8) * N + nb * 32 + tx];
    __syncthreads();
#pragma unroll
    for (int i = 0; i < 4; ++i) {
        int n = nb * 32 + ty + i * 8;
        dst[(size_t)n * K + kb * 32 + tx] = f2bf(Ls[tx][ty + i * 8]);
    }
}

// elementwise f32 -> bf16
__global__ __launch_bounds__(256) void cvt_kernel(const float* __restrict__ in,
                                                  short* __restrict__ out) {
    int i = (blockIdx.x * 256 + threadIdx.x) * 4;
    float4 v = *(const float4*)(in + i);
    short4v o;
    o.x = f2bf(v.x); o.y = f2bf(v.y); o.z = f2bf(v.z); o.w = f2bf(v.w);
    *(short4v*)(out + i) = o;
}

// ---------------------------------------------------------------------------
// V transpose per (b,h): v (BH,S,DK) bf16 -> vt (BH,DK,S) bf16, 64x64 tiles
// ---------------------------------------------------------------------------
__global__ __launch_bounds__(256) void vtrans_kernel(const short* __restrict__ v,
                                                     short* __restrict__ vt) {
    __shared__ short Ls[64 * 72];
    const int bh = blockIdx.y, jt = blockIdx.x * 64;
    const int t = threadIdx.x;
    const int r = t >> 2, cg = t & 3;
    // stage full 64x64 tile: two short8 per thread
    *(short8*)&Ls[r * 72 + cg * 8] =
        *(const short8*)(v + ((size_t)bh * S + jt + r) * DK + cg * 8);
    *(short8*)&Ls[r * 72 + 32 + cg * 8] =
        *(const short8*)(v + ((size_t)bh * S + jt + r) * DK + 32 + cg * 8);
    __syncthreads();
    const int d = t >> 2, sg = t & 3;
    short tmp[16];
#pragma unroll
    for (int i = 0; i < 16; ++i) tmp[i] = Ls[(sg * 16 + i) * 72 + d];
    short* dst = vt + ((size_t)bh * DK + d) * S + jt + sg * 16;
    *(short8*)(dst)     = *(short8*)&tmp[0];
    *(short8*)(dst + 8) = *(short8*)&tmp[8];
}

// ---------------------------------------------------------------------------
// bf16 MFMA GEMM: C = A(M,K) @ Bt(N,K)^T + bias
// 128x128 tile, BK=32, 256 thr (4 waves, 2x2), 4x4 16x16x32 MFMA per wave.
// LDS staged via global_load_lds (16B) with XOR granule swizzle:
//   granule slot(ml,kb) = ml*4 + ((kb + (ml>>1)) & 3)   (2-way frag reads)
// mode 0: Cf = v+bias (f32)
// mode 1: Cb = bf16(relu(v+bias))
// mode 2: v += bias+pe[row%S][col]; Cf = v; Cb = bf16(v)
// mode 3: Cb[z] scattered to (B,H,S,DK) bf16
// ---------------------------------------------------------------------------
__global__ __launch_bounds__(256) void mfma_gemm(
    const short* __restrict__ A, const short* __restrict__ Bt,
    const float* __restrict__ bias, float* __restrict__ Cf,
    short* __restrict__ Cb, int M, int N, int K, int mode,
    const float* __restrict__ pe, long wz, long bz, long cz)
{
    __shared__ short As[128 * 32];
    __shared__ short Bs[128 * 32];

    const int z = blockIdx.z;
    const short* Bz = Bt + (size_t)z * wz;
    const float* bb = bias + (size_t)z * bz;

    const int t = threadIdx.x;
    const int w = t >> 6, lane = t & 63;
    const int wm = w >> 1, wn = w & 1;
    const int ln15 = lane & 15, lq = lane >> 4;
    const int bm = blockIdx.y, bn = blockIdx.x;

    // staging lane mapping (inverse of swizzle)
    const int ml = lane >> 2;
    const int kb = ((lane & 3) - (ml >> 1)) & 3;
    const short* Ag0 = A  + (size_t)(bm * 128 + w * 16 + ml)       * K + kb * 8;
    const short* Ag1 = A  + (size_t)(bm * 128 + (w + 4) * 16 + ml) * K + kb * 8;
    const short* Bg0 = Bz + (size_t)(bn * 128 + w * 16 + ml)       * K + kb * 8;
    const short* Bg1 = Bz + (size_t)(bn * 128 + (w + 4) * 16 + ml) * K + kb * 8;
    short* As0 = As + w * 512;
    short* As1 = As + (w + 4) * 512;
    short* Bs0 = Bs + w * 512;
    short* Bs1 = Bs + (w + 4) * 512;

    floatx4 acc[4][4] = {};

    const int slot = ln15 * 4 + ((lq + (ln15 >> 1)) & 3);   // frag granule slot

    for (int kt = 0; kt < K; kt += 32) {
        __syncthreads();
        __builtin_amdgcn_global_load_lds(
            (const __attribute__((address_space(1))) void*)(Ag0 + kt),
            (__attribute__((address_space(3))) void*)As0, 16, 0, 0);
        __builtin_amdgcn_global_load_lds(
            (const __attribute__((address_space(1))) void*)(Ag1 + kt),
            (__attribute__((address_space(3))) void*)As1, 16, 0, 0);
        __builtin_amdgcn_global_load_lds(
            (const __attribute__((address_space(1))) void*)(Bg0 + kt),
            (__attribute__((address_space(3))) void*)Bs0, 16, 0, 0);
        __builtin_amdgcn_global_load_lds(
            (const __attribute__((address_space(1))) void*)(Bg1 + kt),
            (__attribute__((address_space(3))) void*)Bs1, 16, 0, 0);
        __syncthreads();

        short8 af[4], bf[4];
#pragma unroll
        for (int mt = 0; mt < 4; ++mt) {
            af[mt] = *(const short8*)&As[((wm * 4 + mt) * 64 + slot) * 8];
            bf[mt] = *(const short8*)&Bs[((wn * 4 + mt) * 64 + slot) * 8];
        }
#pragma unroll
        for (int mt = 0; mt < 4; ++mt)
#pragma unroll
            for (int nt = 0; nt < 4; ++nt)
                acc[mt][nt] = __builtin_amdgcn_mfma_f32_16x16x32_bf16(
                    af[mt], bf[nt], acc[mt][nt], 0, 0, 0);
    }

    short* Cbz = Cb + (size_t)z * cz;
#pragma unroll
    for (int mt = 0; mt < 4; ++mt) {
#pragma unroll
        for (int nt = 0; nt < 4; ++nt) {
            const int col = bn * 128 + wn * 64 + nt * 16 + ln15;
            const int row0 = bm * 128 + wm * 64 + mt * 16 + lq * 4;
            const float bc = bb[col];
#pragma unroll
            for (int reg = 0; reg < 4; ++reg) {
                const int r = row0 + reg;
                float v = acc[mt][nt][reg] + bc;
                if (mode == 0) {
                    Cf[(size_t)r * N + col] = v;
                } else if (mode == 1) {
                    Cb[(size_t)r * N + col] = f2bf(fmaxf(v, 0.f));
                } else if (mode == 2) {
                    v += pe[(size_t)(r & (S - 1)) * D + col];
                    Cf[(size_t)r * N + col] = v;
                    Cb[(size_t)r * N + col] = f2bf(v);
                } else {
                    const int bi = r >> 9, si = r & (S - 1);
                    const int hh = col >> 6, dd = col & 63;
                    Cbz[(((size_t)(bi * H + hh) * S + si) * DK + dd)] = f2bf(v);
                }
            }
        }
    }
}

// ---------------------------------------------------------------------------
// bf16 MFMA flash attention. grid (S/64, B*H), 256 thr = 4 waves x 16 q-rows.
// q,k: (BH,S,DK) bf16 ; vt: (BH,DK,S) bf16 ; ctx out: (B,S,D) bf16
// ---------------------------------------------------------------------------
__global__ __launch_bounds__(256) void attn_mfma(
    const short* __restrict__ qg, const short* __restrict__ kg,
    const short* __restrict__ vtg, short* __restrict__ ctx)
{
    __shared__ short Ks[64 * 72];      // [kv][d]
    __shared__ short Vs[64 * 72];      // [dv][kv]
    __shared__ short Ps[4][16 * 72];   // per-wave P [m][kv]

    const int t = threadIdx.x;
    const int w = t >> 6, lane = t & 63;
    const int ln15 = lane & 15, lq = lane >> 4;
    const int bh = blockIdx.y, bi = bh >> 3, hh = bh & 7;
    const int qbase = blockIdx.x * 64 + w * 16;

    short8 qf0, qf1;
    {
        const short* qrow = qg + ((size_t)bh * S + qbase + ln15) * DK;
        qf0 = *(const short8*)(qrow + lq * 8);
        qf1 = *(const short8*)(qrow + 32 + lq * 8);
    }
    floatx4 o[4] = {};
    float mrow[4] = {-1e30f, -1e30f, -1e30f, -1e30f};
    float lrow[4] = {};

    const int sr = t >> 2, scg = t & 3;
    const short* kbase = kg  + (size_t)bh * S * DK;
    const short* vtb   = vtg + (size_t)bh * DK * S;

    for (int jt = 0; jt < S; jt += 64) {
        __syncthreads();
        // full 64x64 tiles: two short8 per thread per array
        *(short8*)&Ks[sr * 72 + scg * 8] =
            *(const short8*)(kbase + (size_t)(jt + sr) * DK + scg * 8);
        *(short8*)&Ks[sr * 72 + 32 + scg * 8] =
            *(const short8*)(kbase + (size_t)(jt + sr) * DK + 32 + scg * 8);
        *(short8*)&Vs[sr * 72 + scg * 8] =
            *(const short8*)(vtb + (size_t)sr * S + jt + scg * 8);
        *(short8*)&Vs[sr * 72 + 32 + scg * 8] =
            *(const short8*)(vtb + (size_t)sr * S + jt + 32 + scg * 8);
        __syncthreads();

        floatx4 sc[4];
#pragma unroll
        for (int nt = 0; nt < 4; ++nt) {
            floatx4 s4 = {};
            short8 kf0 = *(const short8*)&Ks[(nt * 16 + ln15) * 72 + lq * 8];
            short8 kf1 = *(const short8*)&Ks[(nt * 16 + ln15) * 72 + 32 + lq * 8];
            s4 = __builtin_amdgcn_mfma_f32_16x16x32_bf16(qf0, kf0, s4, 0, 0, 0);
            s4 = __builtin_amdgcn_mfma_f32_16x16x32_bf16(qf1, kf1, s4, 0, 0, 0);
#pragma unroll
            for (int r = 0; r < 4; ++r) s4[r] *= 0.125f;
            sc[nt] = s4;
        }

        float rmax[4];
#pragma unroll
        for (int r = 0; r < 4; ++r)
            rmax[r] = fmaxf(fmaxf(sc[0][r], sc[1][r]), fmaxf(sc[2][r], sc[3][r]));
#pragma unroll
        for (int off = 1; off < 16; off <<= 1)
#pragma unroll
            for (int r = 0; r < 4; ++r)
                rmax[r] = fmaxf(rmax[r], __shfl_xor(rmax[r], off));

        float mnew[4], alpha[4], psum[4];
#pragma unroll
        for (int r = 0; r < 4; ++r) {
            mnew[r]  = fmaxf(mrow[r], rmax[r]);
            alpha[r] = __expf(mrow[r] - mnew[r]);
            psum[r]  = 0.f;
        }
#pragma unroll
        for (int nt = 0; nt < 4; ++nt)
#pragma unroll
            for (int r = 0; r < 4; ++r) {
                float p = __expf(sc[nt][r] - mnew[r]);
                psum[r] += p;
                Ps[w][(lq * 4 + r) * 72 + nt * 16 + ln15] = f2bf(p);
            }
#pragma unroll
        for (int off = 1; off < 16; off <<= 1)
#pragma unroll
            for (int r = 0; r < 4; ++r)
                psum[r] += __shfl_xor(psum[r], off);
#pragma unroll
        for (int r = 0; r < 4; ++r) {
            lrow[r] = lrow[r] * alpha[r] + psum[r];
            mrow[r] = mnew[r];
        }
#pragma unroll
        for (int dv = 0; dv < 4; ++dv)
#pragma unroll
            for (int r = 0; r < 4; ++r)
                o[dv][r] *= alpha[r];

        __syncthreads();   // Ps visible (and aligns waves)

        short8 pf0 = *(const short8*)&Ps[w][ln15 * 72 + lq * 8];
        short8 pf1 = *(const short8*)&Ps[w][ln15 * 72 + 32 + lq * 8];
#pragma unroll
        for (int dv = 0; dv < 4; ++dv) {
            short8 vf0 = *(const short8*)&Vs[(dv * 16 + ln15) * 72 + lq * 8];
            short8 vf1 = *(const short8*)&Vs[(dv * 16 + ln15) * 72 + 32 + lq * 8];
            o[dv] = __builtin_amdgcn_mfma_f32_16x16x32_bf16(pf0, vf0, o[dv], 0, 0, 0);
            o[dv] = __builtin_amdgcn_mfma_f32_16x16x32_bf16(pf1, vf1, o[dv], 0, 0, 0);
        }
    }

    float inv[4];
#pragma unroll
    for (int r = 0; r < 4; ++r) inv[r] = 1.f / lrow[r];
#pragma unroll
    for (int dv = 0; dv < 4; ++dv)
#pragma unroll
        for (int r = 0; r < 4; ++r) {
            const int s = qbase + lq * 4 + r;
            const int col = hh * DK + dv * 16 + ln15;
            ctx[((size_t)bi * S + s) * D + col] = f2bf(o[dv][r] * inv[r]);
        }
}

// ---------------------------------------------------------------------------
// Fused residual + LayerNorm, dual f32 + bf16 output
// ---------------------------------------------------------------------------
__global__ __launch_bounds__(128) void ln_kernel(
    const float* __restrict__ a, const float* __restrict__ bres,
    const float* __restrict__ g, const float* __restrict__ beta,
    float* __restrict__ out, short* __restrict__ outb)
{
    const int row = blockIdx.x;
    const int t = threadIdx.x;
    const float4 xa = *(const float4*)(a    + (size_t)row * D + t * 4);
    const float4 xb = *(const float4*)(bres + (size_t)row * D + t * 4);
    float x0 = xa.x + xb.x, x1 = xa.y + xb.y, x2 = xa.z + xb.z, x3 = xa.w + xb.w;
    float s  = x0 + x1 + x2 + x3;
    float s2 = x0 * x0 + x1 * x1 + x2 * x2 + x3 * x3;
#pragma unroll
    for (int o = 32; o > 0; o >>= 1) {
        s  += __shfl_down(s, o);
        s2 += __shfl_down(s2, o);
    }
    __shared__ float red[2][2];
    const int wave = t >> 6;
    if ((t & 63) == 0) { red[wave][0] = s; red[wave][1] = s2; }
    __syncthreads();
    s  = red[0][0] + red[1][0];
    s2 = red[0][1] + red[1][1];
    const float mu  = s * (1.f / (float)D);
    const float var = s2 * (1.f / (float)D) - mu * mu;
    const float r   = rsqrtf(var + EPS);
    const float4 gg = *(const float4*)(g    + t * 4);
    const float4 bb = *(const float4*)(beta + t * 4);
    float4 o;
    o.x = (x0 - mu) * r * gg.x + bb.x;
    o.y = (x1 - mu) * r * gg.y + bb.y;
    o.z = (x2 - mu) * r * gg.z + bb.z;
    o.w = (x3 - mu) * r * gg.w + bb.w;
    *(float4*)(out + (size_t)row * D + t * 4) = o;
    short4v ob;
    ob.x = f2bf(o.x); ob.y = f2bf(o.y); ob.z = f2bf(o.z); ob.w = f2bf(o.w);
    *(short4v*)(outb + (size_t)row * D + t * 4) = ob;
}

// ---------------------------------------------------------------------------
// out[row] = h[row,:] . out_W + out_b ; one wave per row
// ---------------------------------------------------------------------------
__global__ __launch_bounds__(256) void out_kernel(
    const float* __restrict__ h, const float* __restrict__ ow,
    const float* __restrict__ ob, float* __restrict__ out)
{
    const int wave = threadIdx.x >> 6;
    const int lane = threadIdx.x & 63;
    const int row  = blockIdx.x * 4 + wave;
    const float* hp = h + (size_t)row * D;
    float s = 0.f;
#pragma unroll
    for (int u = 0; u < 8; ++u) {
        int d = lane + u * 64;
        s += hp[d] * ow[d];
    }
#pragma unroll
    for (int o = 32; o > 0; o >>= 1) s += __shfl_down(s, o);
    if (lane == 0) out[row] = s + ob[0];
}

// ---------------------------------------------------------------------------
extern "C" void kernel_launch(void* const* d_in, const int* in_sizes, int n_in,
                              void* d_out, int out_size, void* d_ws, size_t ws_size,
                              hipStream_t stream) {
    const float* x       = (const float*)d_in[0];
    const float* in_W    = (const float*)d_in[1];
    const float* in_b    = (const float*)d_in[2];
    const float* rel_emb = (const float*)d_in[3];
    const float* qkvo_W  = (const float*)d_in[4];
    const float* qkvo_b  = (const float*)d_in[5];
    const float* ln_g    = (const float*)d_in[6];
    const float* ln_bb   = (const float*)d_in[7];
    const float* ff_W1   = (const float*)d_in[8];
    const float* ff_b1   = (const float*)d_in[9];
    const float* ff_W2   = (const float*)d_in[10];
    const float* ff_b2   = (const float*)d_in[11];
    const float* out_W   = (const float*)d_in[12];
    const float* out_b   = (const float*)d_in[13];
    float* out = (float*)d_out;

    const size_t HSZ = (size_t)BS * D;             // 4.19M elems
    float* h   = (float*)d_ws;
    float* tmp = h   + HSZ;
    float* h1  = tmp + HSZ;
    float* pe  = h1  + HSZ;                        // S*D floats
    short* h_bf   = (short*)(pe + (size_t)S * D);  // also ctx_bf (aliased)
    short* h1_bf  = h_bf  + HSZ;
    short* xb     = h1_bf + HSZ;                   // BS*IN
    short* qkv_bf = xb + (size_t)BS * IN;          // 4*HSZ (q,k,v,vt / ff1)
    short* wt_qkvo = qkv_bf + 4 * HSZ;             // 4*D*D per layer
    short* wt_ff1  = wt_qkvo + (size_t)4 * D * D;  // F*D
    short* wt_ff2  = wt_ff1  + (size_t)F * D;      // D*F
    short* wt_in   = wt_ff2  + (size_t)D * F;      // D*IN

    short* ctx_bf = h_bf;                          // alias (disjoint lifetime)
    short* ff1_bf = qkv_bf;                        // alias (disjoint lifetime)
    const size_t CZ = (size_t)B * H * S * DK;      // per-matrix q/k/v stride
    short* qb = qkv_bf;
    short* kb = qkv_bf + CZ;
    short* vb = qkv_bf + 2 * CZ;
    short* vt = qkv_bf + 3 * CZ;

    dim3 blk(256);

    pe_kernel<<<dim3(S), blk, 0, stream>>>(rel_emb, pe);
    cvt_kernel<<<dim3(BS * IN / 1024), blk, 0, stream>>>(x, xb);
    wtrans_kernel<<<dim3(D / 32, IN / 32, 1), blk, 0, stream>>>(in_W, wt_in, IN, D);

    // h = x @ in_W + in_b + pe   (f32 + bf16)
    mfma_gemm<<<dim3(D / 128, BS / 128, 1), blk, 0, stream>>>(
        xb, wt_in, in_b, h, h_bf, BS, D, IN, 2, pe, 0, 0, 0);

    for (int l = 0; l < L; ++l) {
        const float* bl = qkvo_b + (size_t)l * 4 * D;
        // per-layer weight transposes (keeps ws footprint small)
        wtrans_kernel<<<dim3(D / 32, D / 32, 4), blk, 0, stream>>>(
            qkvo_W + (size_t)l * 4 * D * D, wt_qkvo, D, D);
        wtrans_kernel<<<dim3(F / 32, D / 32, 1), blk, 0, stream>>>(
            ff_W1 + (size_t)l * D * F, wt_ff1, D, F);
        wtrans_kernel<<<dim3(D / 32, F / 32, 1), blk, 0, stream>>>(
            ff_W2 + (size_t)l * F * D, wt_ff2, F, D);

        // q,k,v projections -> (B,H,S,DK) bf16
        mfma_gemm<<<dim3(D / 128, BS / 128, 3), blk, 0, stream>>>(
            h_bf, wt_qkvo, bl, nullptr, qkv_bf, BS, D, D, 3, nullptr,
            (long)D * D, (long)D, (long)CZ);
        vtrans_kernel<<<dim3(S / 64, B * H), blk, 0, stream>>>(vb, vt);
        attn_mfma<<<dim3(S / 64, B * H), blk, 0, stream>>>(qb, kb, vt, ctx_bf);
        // tmp = ctx @ W_o + b_o  (f32)
        mfma_gemm<<<dim3(D / 128, BS / 128, 1), blk, 0, stream>>>(
            ctx_bf, wt_qkvo + (size_t)3 * D * D, bl + 3 * D, tmp, nullptr,
            BS, D, D, 0, nullptr, 0, 0, 0);
        // h1 = LN(h + tmp)
        ln_kernel<<<dim3(BS), dim3(128), 0, stream>>>(
            h, tmp, ln_g + (size_t)l * 2 * D, ln_bb + (size_t)l * 2 * D, h1, h1_bf);
        // ff1 = relu(h1 @ W1 + b1)  (bf16)
        mfma_gemm<<<dim3(F / 128, BS / 128, 1), blk, 0, stream>>>(
            h1_bf, wt_ff1, ff_b1 + (size_t)l * F, nullptr, ff1_bf,
            BS, F, D, 1, nullptr, 0, 0, 0);
        // tmp = ff1 @ W2 + b2  (f32)
        mfma_gemm<<<dim3(D / 128, BS / 128, 1), blk, 0, stream>>>(
            ff1_bf, wt_ff2, ff_b2 + (size_t)l * D, tmp, nullptr,
            BS, D, F, 0, nullptr, 0, 0, 0);
        // h = LN(h1 + tmp)
        ln_kernel<<<dim3(BS), dim3(128), 0, stream>>>(
            h1, tmp, ln_g + (size_t)l * 2 * D + D, ln_bb + (size_t)l * 2 * D + D,
            h, h_bf);
    }

    out_kernel<<<dim3(BS / 4), blk, 0, stream>>>(h, out_W, out_b, out);
}

// Round 4
// 1247.062 us; speedup vs baseline: 6.5762x; 1.1618x over previous
//
#include <hip/hip_runtime.h>
#include <math.h>

#define B 16
#define S 512
#define IN 64
#define D 512
#define H 8
#define DK 64
#define L 6
#define F 2048
#define BS (B*S)          /* 8192 */
#define EPS 1e-5f

typedef short short8 __attribute__((ext_vector_type(8)));
typedef short short4v __attribute__((ext_vector_type(4)));
typedef float floatx4 __attribute__((ext_vector_type(4)));

static __device__ inline short f2bf(float x) {
    unsigned u = __float_as_uint(x);
    unsigned r = (u + 0x7fffu + ((u >> 16) & 1u)) >> 16;
    return (short)r;
}
static __device__ inline float bf2f(short s) {
    return __uint_as_float(((unsigned)(unsigned short)s) << 16);
}

// ---------------------------------------------------------------------------
// pe[k][d] = (1/S) * sum_q rel_emb[clip(q-k,-32,32)+32][d]   (closed form)
// ---------------------------------------------------------------------------
__global__ __launch_bounds__(256) void pe_kernel(const float* __restrict__ rel_emb,
                                                 float* __restrict__ pe) {
    int k = blockIdx.x;
    int d = threadIdx.x;
    float acc0 = 0.f, acc1 = 0.f;
    for (int r = 0; r < 65; ++r) {
        float w;
        if (r == 0)       w = (float)max(0, k - 31);
        else if (r == 64) w = (float)max(0, S - (k + 32));
        else {
            int qpos = k + r - 32;
            w = (qpos >= 0 && qpos < S) ? 1.f : 0.f;
        }
        acc0 += w * rel_emb[r * D + d];
        acc1 += w * rel_emb[r * D + d + 256];
    }
    pe[k * D + d]       = acc0 * (1.f / (float)S);
    pe[k * D + d + 256] = acc1 * (1.f / (float)S);
}

// ---------------------------------------------------------------------------
// Weight transpose + bf16 convert: src (z,K,N) f32 -> dst (z,N,K) bf16
// ---------------------------------------------------------------------------
__global__ __launch_bounds__(256) void wtrans_kernel(const float* __restrict__ src,
                                                     short* __restrict__ dst,
                                                     int K, int N) {
    __shared__ float Ls[32][33];
    const int z = blockIdx.z, kb = blockIdx.y, nb = blockIdx.x;
    const int tx = threadIdx.x & 31, ty = threadIdx.x >> 5;
    src += (size_t)z * K * N;
    dst += (size_t)z * K * N;
#pragma unroll
    for (int i = 0; i < 4; ++i)
        Ls[ty + i * 8][tx] = src[(size_t)(kb * 32 + ty + i * 8) * N + nb * 32 + tx];
    __syncthreads();
#pragma unroll
    for (int i = 0; i < 4; ++i) {
        int n = nb * 32 + ty + i * 8;
        dst[(size_t)n * K + kb * 32 + tx] = f2bf(Ls[tx][ty + i * 8]);
    }
}

// elementwise f32 -> bf16
__global__ __launch_bounds__(256) void cvt_kernel(const float* __restrict__ in,
                                                  short* __restrict__ out) {
    int i = (blockIdx.x * 256 + threadIdx.x) * 4;
    float4 v = *(const float4*)(in + i);
    short4v o;
    o.x = f2bf(v.x); o.y = f2bf(v.y); o.z = f2bf(v.z); o.w = f2bf(v.w);
    *(short4v*)(out + i) = o;
}

// ---------------------------------------------------------------------------
// V transpose per (b,h): v (BH,S,DK) bf16 -> vt (BH,DK,S) bf16, 64x64 tiles
// ---------------------------------------------------------------------------
__global__ __launch_bounds__(256) void vtrans_kernel(const short* __restrict__ v,
                                                     short* __restrict__ vt) {
    __shared__ short Ls[64 * 72];
    const int bh = blockIdx.y, jt = blockIdx.x * 64;
    const int t = threadIdx.x;
    const int r = t >> 2, cg = t & 3;
    *(short8*)&Ls[r * 72 + cg * 8] =
        *(const short8*)(v + ((size_t)bh * S + jt + r) * DK + cg * 8);
    *(short8*)&Ls[r * 72 + 32 + cg * 8] =
        *(const short8*)(v + ((size_t)bh * S + jt + r) * DK + 32 + cg * 8);
    __syncthreads();
    const int d = t >> 2, sg = t & 3;
    short tmp[16];
#pragma unroll
    for (int i = 0; i < 16; ++i) tmp[i] = Ls[(sg * 16 + i) * 72 + d];
    short* dst = vt + ((size_t)bh * DK + d) * S + jt + sg * 16;
    *(short8*)(dst)     = *(short8*)&tmp[0];
    *(short8*)(dst + 8) = *(short8*)&tmp[8];
}

// ---------------------------------------------------------------------------
// bf16 MFMA GEMM: C = A(M,K) @ Bt(N,K)^T + bias
// 128x128 tile, BK=64 (2 k-panels of 32), 256 thr (4 waves 2x2), 4x4 MFMA/wave.
// LDS via global_load_lds (16B) with XOR granule swizzle; panel-p row-chunk c
// lives at (c*2+p)*512 shorts. Frag slot = ln15*4 + ((lq + (ln15>>1)) & 3).
// mode 0: Cb = bf16(v+bias)
// mode 1: Cb = bf16(relu(v+bias))
// mode 2: Cb = bf16(v + bias + pe[row%S][col])
// mode 3: Cb[z] scattered to (B,H,S,DK) bf16
// ---------------------------------------------------------------------------
#define GLL(SRC, DST) __builtin_amdgcn_global_load_lds( \
    (const __attribute__((address_space(1))) void*)(SRC), \
    (__attribute__((address_space(3))) void*)(DST), 16, 0, 0)

__global__ __launch_bounds__(256) void mfma_gemm(
    const short* __restrict__ A, const short* __restrict__ Bt,
    const float* __restrict__ bias, short* __restrict__ Cb,
    int M, int N, int K, int mode,
    const float* __restrict__ pe, long wz, long bz, long cz)
{
    __shared__ short As[128 * 64];
    __shared__ short Bs[128 * 64];

    const int z = blockIdx.z;
    const short* Bz = Bt + (size_t)z * wz;
    const float* bb = bias + (size_t)z * bz;

    const int t = threadIdx.x;
    const int w = t >> 6, lane = t & 63;
    const int wm = w >> 1, wn = w & 1;
    const int ln15 = lane & 15, lq = lane >> 4;
    const int bm = blockIdx.y, bn = blockIdx.x;

    // staging lane mapping (inverse of swizzle)
    const int ml = lane >> 2;
    const int kb = ((lane & 3) - (ml >> 1)) & 3;
    const short* Ag0 = A  + (size_t)(bm * 128 + w * 16 + ml)       * K + kb * 8;
    const short* Ag1 = A  + (size_t)(bm * 128 + (w + 4) * 16 + ml) * K + kb * 8;
    const short* Bg0 = Bz + (size_t)(bn * 128 + w * 16 + ml)       * K + kb * 8;
    const short* Bg1 = Bz + (size_t)(bn * 128 + (w + 4) * 16 + ml) * K + kb * 8;
    short* A00 = As + (w * 2 + 0) * 512;
    short* A01 = As + (w * 2 + 1) * 512;
    short* A10 = As + ((w + 4) * 2 + 0) * 512;
    short* A11 = As + ((w + 4) * 2 + 1) * 512;
    short* B00 = Bs + (w * 2 + 0) * 512;
    short* B01 = Bs + (w * 2 + 1) * 512;
    short* B10 = Bs + ((w + 4) * 2 + 0) * 512;
    short* B11 = Bs + ((w + 4) * 2 + 1) * 512;

    floatx4 acc[4][4] = {};
    const int slot = ln15 * 4 + ((lq + (ln15 >> 1)) & 3);

    for (int kt = 0; kt < K; kt += 64) {
        __syncthreads();
        GLL(Ag0 + kt,      A00);
        GLL(Ag0 + kt + 32, A01);
        GLL(Ag1 + kt,      A10);
        GLL(Ag1 + kt + 32, A11);
        GLL(Bg0 + kt,      B00);
        GLL(Bg0 + kt + 32, B01);
        GLL(Bg1 + kt,      B10);
        GLL(Bg1 + kt + 32, B11);
        __syncthreads();

#pragma unroll
        for (int p = 0; p < 2; ++p) {
            short8 af[4], bf[4];
#pragma unroll
            for (int mt = 0; mt < 4; ++mt) {
                af[mt] = *(const short8*)&As[(((wm * 4 + mt) * 2 + p) * 64 + slot) * 8];
                bf[mt] = *(const short8*)&Bs[(((wn * 4 + mt) * 2 + p) * 64 + slot) * 8];
            }
#pragma unroll
            for (int mt = 0; mt < 4; ++mt)
#pragma unroll
                for (int nt = 0; nt < 4; ++nt)
                    acc[mt][nt] = __builtin_amdgcn_mfma_f32_16x16x32_bf16(
                        af[mt], bf[nt], acc[mt][nt], 0, 0, 0);
        }
    }

    short* Cbz = Cb + (size_t)z * cz;
#pragma unroll
    for (int mt = 0; mt < 4; ++mt) {
#pragma unroll
        for (int nt = 0; nt < 4; ++nt) {
            const int col = bn * 128 + wn * 64 + nt * 16 + ln15;
            const int row0 = bm * 128 + wm * 64 + mt * 16 + lq * 4;
            const float bc = bb[col];
#pragma unroll
            for (int reg = 0; reg < 4; ++reg) {
                const int r = row0 + reg;
                float v = acc[mt][nt][reg] + bc;
                if (mode == 1) v = fmaxf(v, 0.f);
                else if (mode == 2) v += pe[(size_t)(r & (S - 1)) * D + col];
                if (mode == 3) {
                    const int bi = r >> 9, si = r & (S - 1);
                    const int hh = col >> 6, dd = col & 63;
                    Cbz[(((size_t)(bi * H + hh) * S + si) * DK + dd)] = f2bf(v);
                } else {
                    Cb[(size_t)r * N + col] = f2bf(v);
                }
            }
        }
    }
}

// ---------------------------------------------------------------------------
// bf16 MFMA flash attention. grid (S/64, B*H), 256 thr = 4 waves x 16 q-rows.
// q,k: (BH,S,DK) bf16 ; vt: (BH,DK,S) bf16 ; ctx out: (B,S,D) bf16
// ---------------------------------------------------------------------------
__global__ __launch_bounds__(256) void attn_mfma(
    const short* __restrict__ qg, const short* __restrict__ kg,
    const short* __restrict__ vtg, short* __restrict__ ctx)
{
    __shared__ short Ks[64 * 72];      // [kv][d]
    __shared__ short Vs[64 * 72];      // [dv][kv]
    __shared__ short Ps[4][16 * 72];   // per-wave P [m][kv] (wave-private)

    const int t = threadIdx.x;
    const int w = t >> 6, lane = t & 63;
    const int ln15 = lane & 15, lq = lane >> 4;
    const int bh = blockIdx.y, bi = bh >> 3, hh = bh & 7;
    const int qbase = blockIdx.x * 64 + w * 16;

    short8 qf0, qf1;
    {
        const short* qrow = qg + ((size_t)bh * S + qbase + ln15) * DK;
        qf0 = *(const short8*)(qrow + lq * 8);
        qf1 = *(const short8*)(qrow + 32 + lq * 8);
    }
    floatx4 o[4] = {};
    float mrow[4] = {-1e30f, -1e30f, -1e30f, -1e30f};
    float lrow[4] = {};

    const int sr = t >> 2, scg = t & 3;
    const short* kbase = kg  + (size_t)bh * S * DK;
    const short* vtb   = vtg + (size_t)bh * DK * S;

    for (int jt = 0; jt < S; jt += 64) {
        __syncthreads();
        *(short8*)&Ks[sr * 72 + scg * 8] =
            *(const short8*)(kbase + (size_t)(jt + sr) * DK + scg * 8);
        *(short8*)&Ks[sr * 72 + 32 + scg * 8] =
            *(const short8*)(kbase + (size_t)(jt + sr) * DK + 32 + scg * 8);
        *(short8*)&Vs[sr * 72 + scg * 8] =
            *(const short8*)(vtb + (size_t)sr * S + jt + scg * 8);
        *(short8*)&Vs[sr * 72 + 32 + scg * 8] =
            *(const short8*)(vtb + (size_t)sr * S + jt + 32 + scg * 8);
        __syncthreads();

        floatx4 sc[4];
#pragma unroll
        for (int nt = 0; nt < 4; ++nt) {
            floatx4 s4 = {};
            short8 kf0 = *(const short8*)&Ks[(nt * 16 + ln15) * 72 + lq * 8];
            short8 kf1 = *(const short8*)&Ks[(nt * 16 + ln15) * 72 + 32 + lq * 8];
            s4 = __builtin_amdgcn_mfma_f32_16x16x32_bf16(qf0, kf0, s4, 0, 0, 0);
            s4 = __builtin_amdgcn_mfma_f32_16x16x32_bf16(qf1, kf1, s4, 0, 0, 0);
#pragma unroll
            for (int r = 0; r < 4; ++r) s4[r] *= 0.125f;
            sc[nt] = s4;
        }

        float rmax[4];
#pragma unroll
        for (int r = 0; r < 4; ++r)
            rmax[r] = fmaxf(fmaxf(sc[0][r], sc[1][r]), fmaxf(sc[2][r], sc[3][r]));
#pragma unroll
        for (int off = 1; off < 16; off <<= 1)
#pragma unroll
            for (int r = 0; r < 4; ++r)
                rmax[r] = fmaxf(rmax[r], __shfl_xor(rmax[r], off));

        float mnew[4], alpha[4], psum[4];
#pragma unroll
        for (int r = 0; r < 4; ++r) {
            mnew[r]  = fmaxf(mrow[r], rmax[r]);
            alpha[r] = __expf(mrow[r] - mnew[r]);
            psum[r]  = 0.f;
        }
#pragma unroll
        for (int nt = 0; nt < 4; ++nt)
#pragma unroll
            for (int r = 0; r < 4; ++r) {
                float p = __expf(sc[nt][r] - mnew[r]);
                psum[r] += p;
                Ps[w][(lq * 4 + r) * 72 + nt * 16 + ln15] = f2bf(p);
            }
#pragma unroll
        for (int off = 1; off < 16; off <<= 1)
#pragma unroll
            for (int r = 0; r < 4; ++r)
                psum[r] += __shfl_xor(psum[r], off);
#pragma unroll
        for (int r = 0; r < 4; ++r) {
            lrow[r] = lrow[r] * alpha[r] + psum[r];
            mrow[r] = mnew[r];
        }
#pragma unroll
        for (int dv = 0; dv < 4; ++dv)
#pragma unroll
            for (int r = 0; r < 4; ++r)
                o[dv][r] *= alpha[r];

        // NOTE: no barrier here — Ps[w] is written and read by wave w only;
        // within-wave LDS ordering is guaranteed via lgkmcnt.
        short8 pf0 = *(const short8*)&Ps[w][ln15 * 72 + lq * 8];
        short8 pf1 = *(const short8*)&Ps[w][ln15 * 72 + 32 + lq * 8];
#pragma unroll
        for (int dv = 0; dv < 4; ++dv) {
            short8 vf0 = *(const short8*)&Vs[(dv * 16 + ln15) * 72 + lq * 8];
            short8 vf1 = *(const short8*)&Vs[(dv * 16 + ln15) * 72 + 32 + lq * 8];
            o[dv] = __builtin_amdgcn_mfma_f32_16x16x32_bf16(pf0, vf0, o[dv], 0, 0, 0);
            o[dv] = __builtin_amdgcn_mfma_f32_16x16x32_bf16(pf1, vf1, o[dv], 0, 0, 0);
        }
    }

    float inv[4];
#pragma unroll
    for (int r = 0; r < 4; ++r) inv[r] = 1.f / lrow[r];
#pragma unroll
    for (int dv = 0; dv < 4; ++dv)
#pragma unroll
        for (int r = 0; r < 4; ++r) {
            const int s = qbase + lq * 4 + r;
            const int col = hh * DK + dv * 16 + ln15;
            ctx[((size_t)bi * S + s) * D + col] = f2bf(o[dv][r] * inv[r]);
        }
}

// ---------------------------------------------------------------------------
// Fused residual + LayerNorm, bf16 in / bf16 out (f32 internal)
// ---------------------------------------------------------------------------
__global__ __launch_bounds__(128) void ln_kernel(
    const short* __restrict__ a, const short* __restrict__ bres,
    const float* __restrict__ g, const float* __restrict__ beta,
    short* __restrict__ outb)
{
    const int row = blockIdx.x;
    const int t = threadIdx.x;
    const short4v xa = *(const short4v*)(a    + (size_t)row * D + t * 4);
    const short4v xb = *(const short4v*)(bres + (size_t)row * D + t * 4);
    float x0 = bf2f(xa.x) + bf2f(xb.x), x1 = bf2f(xa.y) + bf2f(xb.y);
    float x2 = bf2f(xa.z) + bf2f(xb.z), x3 = bf2f(xa.w) + bf2f(xb.w);
    float s  = x0 + x1 + x2 + x3;
    float s2 = x0 * x0 + x1 * x1 + x2 * x2 + x3 * x3;
#pragma unroll
    for (int o = 32; o > 0; o >>= 1) {
        s  += __shfl_down(s, o);
        s2 += __shfl_down(s2, o);
    }
    __shared__ float red[2][2];
    const int wave = t >> 6;
    if ((t & 63) == 0) { red[wave][0] = s; red[wave][1] = s2; }
    __syncthreads();
    s  = red[0][0] + red[1][0];
    s2 = red[0][1] + red[1][1];
    const float mu  = s * (1.f / (float)D);
    const float var = s2 * (1.f / (float)D) - mu * mu;
    const float r   = rsqrtf(var + EPS);
    const float4 gg = *(const float4*)(g    + t * 4);
    const float4 bb = *(const float4*)(beta + t * 4);
    short4v ob;
    ob.x = f2bf((x0 - mu) * r * gg.x + bb.x);
    ob.y = f2bf((x1 - mu) * r * gg.y + bb.y);
    ob.z = f2bf((x2 - mu) * r * gg.z + bb.z);
    ob.w = f2bf((x3 - mu) * r * gg.w + bb.w);
    *(short4v*)(outb + (size_t)row * D + t * 4) = ob;
}

// ---------------------------------------------------------------------------
// out[row] = h[row,:] . out_W + out_b ; one wave per row (h is bf16)
// ---------------------------------------------------------------------------
__global__ __launch_bounds__(256) void out_kernel(
    const short* __restrict__ h, const float* __restrict__ ow,
    const float* __restrict__ ob, float* __restrict__ out)
{
    const int wave = threadIdx.x >> 6;
    const int lane = threadIdx.x & 63;
    const int row  = blockIdx.x * 4 + wave;
    const short* hp = h + (size_t)row * D;
    float s = 0.f;
#pragma unroll
    for (int u = 0; u < 8; ++u) {
        int d = lane + u * 64;
        s += bf2f(hp[d]) * ow[d];
    }
#pragma unroll
    for (int o = 32; o > 0; o >>= 1) s += __shfl_down(s, o);
    if (lane == 0) out[row] = s + ob[0];
}

// ---------------------------------------------------------------------------
extern "C" void kernel_launch(void* const* d_in, const int* in_sizes, int n_in,
                              void* d_out, int out_size, void* d_ws, size_t ws_size,
                              hipStream_t stream) {
    const float* x       = (const float*)d_in[0];
    const float* in_W    = (const float*)d_in[1];
    const float* in_b    = (const float*)d_in[2];
    const float* rel_emb = (const float*)d_in[3];
    const float* qkvo_W  = (const float*)d_in[4];
    const float* qkvo_b  = (const float*)d_in[5];
    const float* ln_g    = (const float*)d_in[6];
    const float* ln_bb   = (const float*)d_in[7];
    const float* ff_W1   = (const float*)d_in[8];
    const float* ff_b1   = (const float*)d_in[9];
    const float* ff_W2   = (const float*)d_in[10];
    const float* ff_b2   = (const float*)d_in[11];
    const float* out_W   = (const float*)d_in[12];
    const float* out_b   = (const float*)d_in[13];
    float* out = (float*)d_out;

    const size_t HSZ = (size_t)BS * D;              // 4.19M elems
    float* pe     = (float*)d_ws;                   // S*D f32
    short* h_bf   = (short*)(pe + (size_t)S * D);
    short* h1_bf  = h_bf  + HSZ;
    short* tmp_bf = h1_bf + HSZ;
    short* qkv_bf = tmp_bf + HSZ;                   // 4*HSZ: q,k,v,vt (ff1 alias)
    short* xb     = qkv_bf + 4 * HSZ;               // BS*IN
    short* wt_qkvo = xb + (size_t)BS * IN;          // L*4*D*D
    short* wt_ff1  = wt_qkvo + (size_t)L * 4 * D * D;  // L*D*F
    short* wt_ff2  = wt_ff1  + (size_t)L * D * F;      // L*F*D
    short* wt_in   = wt_ff2  + (size_t)L * F * D;      // D*IN

    const size_t CZ = (size_t)B * H * S * DK;       // == HSZ
    short* qb = qkv_bf;
    short* kb = qkv_bf + CZ;
    short* vb = qkv_bf + 2 * CZ;
    short* vt = qkv_bf + 3 * CZ;
    short* ctx_bf = vb;                             // alias (v dead after vtrans)
    short* ff1_bf = qkv_bf;                         // alias (qkv dead after attn-out)

    dim3 blk(256);

    // --- prologue: pe, input cvt, ALL weight transposes (hoisted) ---
    pe_kernel<<<dim3(S), blk, 0, stream>>>(rel_emb, pe);
    cvt_kernel<<<dim3(BS * IN / 1024), blk, 0, stream>>>(x, xb);
    wtrans_kernel<<<dim3(D / 32, IN / 32, 1), blk, 0, stream>>>(in_W, wt_in, IN, D);
    wtrans_kernel<<<dim3(D / 32, D / 32, 4 * L), blk, 0, stream>>>(qkvo_W, wt_qkvo, D, D);
    wtrans_kernel<<<dim3(F / 32, D / 32, L), blk, 0, stream>>>(ff_W1, wt_ff1, D, F);
    wtrans_kernel<<<dim3(D / 32, F / 32, L), blk, 0, stream>>>(ff_W2, wt_ff2, F, D);

    // h = x @ in_W + in_b + pe   (bf16)
    mfma_gemm<<<dim3(D / 128, BS / 128, 1), blk, 0, stream>>>(
        xb, wt_in, in_b, h_bf, BS, D, IN, 2, pe, 0, 0, 0);

    for (int l = 0; l < L; ++l) {
        const float* bl = qkvo_b + (size_t)l * 4 * D;
        // q,k,v projections -> (B,H,S,DK) bf16
        mfma_gemm<<<dim3(D / 128, BS / 128, 3), blk, 0, stream>>>(
            h_bf, wt_qkvo + (size_t)l * 4 * D * D, bl, qkv_bf, BS, D, D, 3,
            nullptr, (long)D * D, (long)D, (long)CZ);
        vtrans_kernel<<<dim3(S / 64, B * H), blk, 0, stream>>>(vb, vt);
        attn_mfma<<<dim3(S / 64, B * H), blk, 0, stream>>>(qb, kb, vt, ctx_bf);
        // tmp = ctx @ W_o + b_o  (bf16)
        mfma_gemm<<<dim3(D / 128, BS / 128, 1), blk, 0, stream>>>(
            ctx_bf, wt_qkvo + (size_t)(l * 4 + 3) * D * D, bl + 3 * D, tmp_bf,
            BS, D, D, 0, nullptr, 0, 0, 0);
        // h1 = LN(h + tmp)
        ln_kernel<<<dim3(BS), dim3(128), 0, stream>>>(
            h_bf, tmp_bf, ln_g + (size_t)l * 2 * D, ln_bb + (size_t)l * 2 * D, h1_bf);
        // ff1 = relu(h1 @ W1 + b1)  (bf16)
        mfma_gemm<<<dim3(F / 128, BS / 128, 1), blk, 0, stream>>>(
            h1_bf, wt_ff1 + (size_t)l * D * F, ff_b1 + (size_t)l * F, ff1_bf,
            BS, F, D, 1, nullptr, 0, 0, 0);
        // tmp = ff1 @ W2 + b2  (bf16)
        mfma_gemm<<<dim3(D / 128, BS / 128, 1), blk, 0, stream>>>(
            ff1_bf, wt_ff2 + (size_t)l * F * D, ff_b2 + (size_t)l * D, tmp_bf,
            BS, D, F, 0, nullptr, 0, 0, 0);
        // h = LN(h1 + tmp)
        ln_kernel<<<dim3(BS), dim3(128), 0, stream>>>(
            h1_bf, tmp_bf, ln_g + (size_t)l * 2 * D + D, ln_bb + (size_t)l * 2 * D + D,
            h_bf);
    }

    out_kernel<<<dim3(BS / 4), blk, 0, stream>>>(h_bf, out_W, out_b, out);
}